// Round 5
// baseline (64.459 us; speedup 1.0000x reference)
//
#include <hip/hip_runtime.h>

// PARAFAC CP-rank-16 query kernel — minimal single-launch direct-gather.
// U,V,W: [R=16][D=400] row-major f32. index: [N][3] int32. out: [N] f32.
// out[n] = sum_r U[r,i]*V[r,j]*W[r,k]
//
// Rationale (R4 hypothesis test): factor tables total 76.8 KB -> fully
// L2-resident; per-r rows (3 x 1.6 KB) stay L1-hot since all waves walk r in
// lockstep. No LDS, no staging, no extra launch. If dur_us stays ~60 us this
// confirms the measured time is dominated by a fixed harness floor
// (d_ws re-poison fill ~40 us + input restores), not by the kernel.

#define RANK 16
#define DIM  400

__global__ __launch_bounds__(256)
void cp_direct(const float* __restrict__ U,
               const float* __restrict__ V,
               const float* __restrict__ W,
               const int* __restrict__ idx,
               float* __restrict__ out, int n) {
    int t = blockIdx.x * blockDim.x + threadIdx.x;
    if (t >= n) return;
    int i = idx[3 * t + 0];
    int j = idx[3 * t + 1];
    int k = idx[3 * t + 2];
    float acc = 0.0f;
#pragma unroll
    for (int r = 0; r < RANK; ++r) {
        acc = fmaf(U[r * DIM + i], V[r * DIM + j] * W[r * DIM + k], acc);
    }
    out[t] = acc;
}

extern "C" void kernel_launch(void* const* d_in, const int* in_sizes, int n_in,
                              void* d_out, int out_size, void* d_ws, size_t ws_size,
                              hipStream_t stream) {
    const float* U   = (const float*)d_in[0];
    const float* V   = (const float*)d_in[1];
    const float* W   = (const float*)d_in[2];
    const int*   idx = (const int*)d_in[3];
    float*       out = (float*)d_out;
    const int n = out_size;  // 100000 queries

    int blk = 256;
    cp_direct<<<(n + blk - 1) / blk, blk, 0, stream>>>(U, V, W, idx, out, n);
}

// Round 6
// 60.890 us; speedup vs baseline: 1.0586x; 1.0586x over previous
//
#include <hip/hip_runtime.h>

// PARAFAC CP-rank-16 query kernel, fused single-launch version (FINAL).
// U,V,W: [R=16][D=400] row-major f32. index: [N][3] int32. out: [N] f32.
// out[n] = sum_r U[r,i]*V[r,j]*W[r,k]
//
// Measured trajectory: R2 two-launch=63.8us, R3 this kernel=61.5us,
// R5 direct-gather=64.5us. All within noise of a ~59us fixed harness floor
// (268MB d_ws re-poison fill @40us + restores inside the timed window);
// kernel-attributable time ~2-5us. This variant measured best and has the
// best latency mechanics: each block stages all three factor tables
// (76.8 KB, native layout, coalesced float4) into LDS, then each thread
// answers one query with 48 ds_read_b32 (~random banks, ~2-way avg conflict
// = free per m136) instead of 48 ~200-cycle L2 hits at low occupancy.

#define RANK 16
#define DIM  400
#define PER  (RANK * DIM)     // 6400 floats per factor
#define PER4 (PER / 4)        // 1600 float4 per factor
#define BLOCK 512
#define QPB   512             // queries per block (1 per thread)

__global__ __launch_bounds__(BLOCK)
void cp_fused(const float* __restrict__ U,
              const float* __restrict__ V,
              const float* __restrict__ W,
              const int* __restrict__ idx,
              float* __restrict__ out, int n) {
    __shared__ float lds[3 * PER];   // 76.8 KB

    // Stage all three factors, vectorized, zero bank conflicts on write.
    {
        const float4* U4 = (const float4*)U;
        const float4* V4 = (const float4*)V;
        const float4* W4 = (const float4*)W;
        float4* L4 = (float4*)lds;
        for (int c = threadIdx.x; c < PER4; c += BLOCK) {
            L4[c]            = U4[c];
            L4[c + PER4]     = V4[c];
            L4[c + 2 * PER4] = W4[c];
        }
    }
    __syncthreads();

    int t = blockIdx.x * QPB + threadIdx.x;
    if (t >= n) return;

    int i = idx[3 * t + 0];
    int j = idx[3 * t + 1];
    int k = idx[3 * t + 2];

    const float* Ul = lds;
    const float* Vl = lds + PER;
    const float* Wl = lds + 2 * PER;

    float acc = 0.0f;
#pragma unroll
    for (int r = 0; r < RANK; ++r) {
        acc = fmaf(Ul[r * DIM + i], Vl[r * DIM + j] * Wl[r * DIM + k], acc);
    }
    out[t] = acc;
}

extern "C" void kernel_launch(void* const* d_in, const int* in_sizes, int n_in,
                              void* d_out, int out_size, void* d_ws, size_t ws_size,
                              hipStream_t stream) {
    const float* U   = (const float*)d_in[0];
    const float* V   = (const float*)d_in[1];
    const float* W   = (const float*)d_in[2];
    const int*   idx = (const int*)d_in[3];
    float*       out = (float*)d_out;
    const int n = out_size;  // 100000 queries

    int grid = (n + QPB - 1) / QPB;  // 196 blocks
    cp_fused<<<grid, BLOCK, 0, stream>>>(U, V, W, idx, out, n);
}